// Round 3
// baseline (1566.266 us; speedup 1.0000x reference)
//
#include <hip/hip_runtime.h>
#include <hip/hip_bf16.h>

#define HWs 50176      // 224*224
#define WID 224
#define OHW 200704     // 448*448

// ---------------- K0: transpose conv weights OIHW[oc][ic][tap] -> [ic][tap][oc] (oc contiguous)
// 5 layers (head + 4 blocks), 90000 floats each.
__global__ void k_wt(const float* __restrict__ w_head, const float* __restrict__ w_blk,
                     float* __restrict__ wt) {
  int l = blockIdx.y;
  int i = blockIdx.x * 256 + threadIdx.x;
  if (i >= 90000) return;
  const float* src = (l == 0) ? w_head : (w_blk + (l - 1) * 90000);
  int oc = i / 900, rem = i - oc * 900;       // rem = ic*9+tap
  wt[l * 90000 + rem * 100 + oc] = src[i];
}

// ---------------- K1: bilinear warp of feat_0/feat_1 + concat into x_in (100 planes fp32)
__global__ void k_warp(const float* __restrict__ f0, const float* __restrict__ f1,
                       const float* __restrict__ fd, const float* __restrict__ fl,
                       float* __restrict__ xin) {
  int p = blockIdx.x * 256 + threadIdx.x;          // 196*256 == 50176 exact
  int y = p / WID, x = p - y * WID;
  float fx0 = fl[p];
  float fy0 = fl[HWs + p];
  float fx1 = fl[2 * HWs + p];
  float fy1 = fl[3 * HWs + p];

  #pragma unroll
  for (int img = 0; img < 2; ++img) {
    const float* src = img ? f1 : f0;
    float fx = img ? fx1 : fx0;
    float fy = img ? fy1 : fy0;
    float px = (float)x + fx, py = (float)y + fy;
    float x0f = floorf(px), y0f = floorf(py);
    float wx = px - x0f, wy = py - y0f;
    int x0 = (int)fminf(fmaxf(x0f,       0.f), 223.f);
    int x1 = (int)fminf(fmaxf(x0f + 1.f, 0.f), 223.f);
    int y0 = (int)fminf(fmaxf(y0f,       0.f), 223.f);
    int y1 = (int)fminf(fmaxf(y0f + 1.f, 0.f), 223.f);
    float w00 = (1.f - wx) * (1.f - wy), w01 = wx * (1.f - wy);
    float w10 = (1.f - wx) * wy,         w11 = wx * wy;
    int i00 = y0 * WID + x0, i01 = y0 * WID + x1;
    int i10 = y1 * WID + x0, i11 = y1 * WID + x1;
    float* dst = xin + img * 32 * HWs;
    for (int c = 0; c < 32; ++c) {
      const float* pl = src + c * HWs;
      dst[c * HWs + p] = w00 * pl[i00] + w01 * pl[i01]
                       + w10 * pl[i10] + w11 * pl[i11];
    }
  }
  for (int c = 0; c < 32; ++c) xin[(64 + c) * HWs + p] = fd[c * HWs + p];
  xin[96 * HWs + p] = fx0; xin[97 * HWs + p] = fy0;
  xin[98 * HWs + p] = fx1; xin[99 * HWs + p] = fy1;
}

// ---------------- K2: 3x3 conv 100->100 + PReLU + space_mask
// grid (28,28); block 256 = 4 waves. Each block: 8x8 px tile, ALL 100 oc.
// wave q computes oc [25q, 25q+25). Patch (10x10x100 = 39KB) staged once in LDS.
// Weights read as wave-uniform scalar loads from transposed layout [ic][tap][oc].
// head: prelu(conv)*m; blocks: prelu(conv*m) — identical for m>=0 (space_mask in [0,1)).
__global__ __launch_bounds__(256, 4) void k_conv(
    const float* __restrict__ in, const float* __restrict__ wt,
    const float* __restrict__ avec, const float* __restrict__ mask,
    float* __restrict__ outp) {
  __shared__ float patch[10000];                   // [ic][ry*10+rx], 40000 B
  int tid = threadIdx.x;
  int bx = blockIdx.x, by = blockIdx.y;
  int ox = bx * 8 - 1, oy = by * 8 - 1;

  for (int i = tid; i < 10000; i += 256) {
    int ic = i / 100, rem = i - ic * 100;
    int ry = rem / 10, rx = rem - ry * 10;
    int gy = oy + ry, gx = ox + rx;
    float v = 0.f;
    if ((unsigned)gy < 224u && (unsigned)gx < 224u)
      v = in[ic * HWs + gy * WID + gx];
    patch[i] = v;
  }
  __syncthreads();

  int lane = tid & 63;
  int ocq = __builtin_amdgcn_readfirstlane(tid >> 6);   // wave-uniform 0..3
  int px = lane & 7, py = lane >> 3;
  const float* wq = wt + 25 * ocq;                 // + (ic*9+tap)*100 + o

  float acc[25];
  #pragma unroll
  for (int o = 0; o < 25; ++o) acc[o] = 0.f;

  for (int ic = 0; ic < 100; ++ic) {
    const float* pp = patch + ic * 100 + py * 10 + px;
    const float* wic = wq + ic * 900;
    #pragma unroll
    for (int dy = 0; dy < 3; ++dy) {
      #pragma unroll
      for (int dx = 0; dx < 3; ++dx) {
        float pv = pp[dy * 10 + dx];
        const float* w25 = wic + (dy * 3 + dx) * 100;
        #pragma unroll
        for (int o = 0; o < 25; ++o)
          acc[o] = fmaf(w25[o], pv, acc[o]);
      }
    }
  }

  int gx0 = bx * 8 + px, gy0 = by * 8 + py;
  float m = mask[gy0 * WID + gx0];
  #pragma unroll
  for (int o = 0; o < 25; ++o) {
    int oc = 25 * ocq + o;
    float al = avec[oc];                           // wave-uniform scalar load
    float z = acc[o];
    outp[oc * HWs + gy0 * WID + gx0] = (z >= 0.f ? z : al * z) * m;
  }
}

// ---------------- K3: incremental einsum: xlast[o][p] (+)= sum_{il<100} w_last[o][base+il]*x[il][p]
// init!=0: xlast = b_last + contribution (first layer); else accumulate.
__global__ void k_acc(const float* __restrict__ x, const float* __restrict__ wlast,
                      const float* __restrict__ blast, float* __restrict__ xlast,
                      int base, int init) {
  __shared__ __align__(16) float wl[100 * 36];   // transposed [il][o], 14.4KB
  int tid = threadIdx.x;
  int p = blockIdx.x * 256 + tid;
  for (int j = tid; j < 100 * 36; j += 256) {
    int il = j / 36, o = j - il * 36;
    wl[j] = wlast[o * 500 + base + il];
  }
  __syncthreads();
  float acc[36];
  #pragma unroll
  for (int o = 0; o < 36; ++o) acc[o] = init ? blast[o] : xlast[o * HWs + p];
  for (int il = 0; il < 100; ++il) {
    float f = x[il * HWs + p];
    const float4* wp = (const float4*)&wl[il * 36];
    #pragma unroll
    for (int j = 0; j < 9; ++j) {
      float4 t = wp[j];
      acc[4*j]   += t.x * f;
      acc[4*j+1] += t.y * f;
      acc[4*j+2] += t.z * f;
      acc[4*j+3] += t.w * f;
    }
  }
  #pragma unroll
  for (int o = 0; o < 36; ++o) xlast[o * HWs + p] = acc[o];
}

// ---------------- K4: smn = conv3x3(xlast[4:36], w_mask) + b_mask (2 ch), fp64 accum
__global__ void k_smn(const float* __restrict__ xlast, const float* __restrict__ wmask,
                      const float* __restrict__ bmask, float* __restrict__ smn) {
  __shared__ float wm[576];
  int tid = threadIdx.x;
  for (int j = tid; j < 576; j += 256) wm[j] = wmask[j];
  __syncthreads();
  int p = blockIdx.x * 256 + tid;
  int y = p / WID, x = p - y * WID;
  double a0 = 0.0, a1 = 0.0;
  for (int ic = 0; ic < 32; ++ic) {
    const float* pl = xlast + (4 + ic) * HWs;
    #pragma unroll
    for (int dy = -1; dy <= 1; ++dy) {
      int gy = y + dy;
      if ((unsigned)gy < 224u) {
        #pragma unroll
        for (int dx = -1; dx <= 1; ++dx) {
          int gx = x + dx;
          if ((unsigned)gx < 224u) {
            double v = (double)pl[gy * WID + gx];
            int t = (dy + 1) * 3 + (dx + 1);
            a0 += (double)wm[ic * 9 + t] * v;        // oc 0
            a1 += (double)wm[288 + ic * 9 + t] * v;  // oc 1
          }
        }
      }
    }
  }
  smn[p]       = (float)(a0 + (double)bmask[0]);
  smn[HWs + p] = (float)(a1 + (double)bmask[1]);
}

// ---------------- K5: 2x bilinear upsample (jax.image.resize 'linear') + mask compare
__global__ void k_upsample(const float* __restrict__ xlast, const float* __restrict__ smn,
                           const float* __restrict__ smask, float* __restrict__ out) {
  int q = blockIdx.x * 256 + threadIdx.x;          // 784*256 == 200704 exact
  int oy = q / 448, ox = q - oy * 448;
  int ky = oy >> 1, kx = ox >> 1;
  int r0, r1, c0, c1; float wy0, wy1, wx0, wx1;
  if (oy & 1) { r0 = ky; r1 = (ky < 223) ? ky + 1 : 223; wy0 = 0.75f; wy1 = 0.25f; }
  else        { r0 = (ky > 0) ? ky - 1 : 0; r1 = ky;     wy0 = 0.25f; wy1 = 0.75f; }
  if (ox & 1) { c0 = kx; c1 = (kx < 223) ? kx + 1 : 223; wx0 = 0.75f; wx1 = 0.25f; }
  else        { c0 = (kx > 0) ? kx - 1 : 0; c1 = kx;     wx0 = 0.25f; wx1 = 0.75f; }
  float w00 = wy0 * wx0, w01 = wy0 * wx1, w10 = wy1 * wx0, w11 = wy1 * wx1;
  int i00 = r0 * WID + c0, i01 = r0 * WID + c1, i10 = r1 * WID + c0, i11 = r1 * WID + c1;
  for (int ch = 0; ch < 36; ++ch) {
    const float* pl = xlast + ch * HWs;
    out[ch * OHW + q] = w00 * pl[i00] + w01 * pl[i01] + w10 * pl[i10] + w11 * pl[i11];
  }
  double s0 = (double)w00 * smn[i00] + (double)w01 * smn[i01]
            + (double)w10 * smn[i10] + (double)w11 * smn[i11];
  const float* s1p = smn + HWs;
  double s1 = (double)w00 * s1p[i00] + (double)w01 * s1p[i01]
            + (double)w10 * s1p[i10] + (double)w11 * s1p[i11];
  float mu = smask[ky * WID + kx];
  out[36 * OHW + q] = (s0 > s1) ? mu : 0.f;
}

extern "C" void kernel_launch(void* const* d_in, const int* in_sizes, int n_in,
                              void* d_out, int out_size, void* d_ws, size_t ws_size,
                              hipStream_t stream) {
  const float* feat0   = (const float*)d_in[0];
  const float* feat1   = (const float*)d_in[1];
  const float* featd   = (const float*)d_in[2];
  const float* flow    = (const float*)d_in[3];
  const float* smask   = (const float*)d_in[4];
  const float* w_head  = (const float*)d_in[5];
  const float* a_head  = (const float*)d_in[6];
  const float* w_blk   = (const float*)d_in[7];
  const float* a_blk   = (const float*)d_in[8];
  const float* w_last  = (const float*)d_in[9];
  const float* b_last  = (const float*)d_in[10];
  const float* w_mask  = (const float*)d_in[11];
  const float* b_mask  = (const float*)d_in[12];

  // ws layout: ping-pong bufs + xlast + smn + transposed weights (~49.6 MB)
  float* bufA  = (float*)d_ws;            // 100 planes
  float* bufB  = bufA + 100 * HWs;        // 100 planes
  float* xlast = bufB + 100 * HWs;        // 36 planes
  float* smn   = xlast + 36 * HWs;        // 2 planes
  float* wt    = smn + 2 * HWs;           // 5*90000 floats

  k_wt<<<dim3(352, 5), 256, 0, stream>>>(w_head, w_blk, wt);
  k_warp<<<196, 256, 0, stream>>>(feat0, feat1, featd, flow, bufA);

  dim3 cgrid(28, 28);
  // head: bufA -> bufB, then accumulate einsum slice 0
  k_conv<<<cgrid, 256, 0, stream>>>(bufA, wt, a_head, smask, bufB);
  k_acc<<<196, 256, 0, stream>>>(bufB, w_last, b_last, xlast, 0, 1);
  // blocks: ping-pong bufB<->bufA
  float* src = bufB; float* dst = bufA;
  for (int l = 0; l < 4; ++l) {
    k_conv<<<cgrid, 256, 0, stream>>>(src, wt + (l + 1) * 90000, a_blk + l * 100, smask, dst);
    k_acc<<<196, 256, 0, stream>>>(dst, w_last, b_last, xlast, (l + 1) * 100, 0);
    float* t = src; src = dst; dst = t;
  }

  k_smn<<<196, 256, 0, stream>>>(xlast, w_mask, b_mask, smn);
  k_upsample<<<784, 256, 0, stream>>>(xlast, smn, smask, (float*)d_out);
}

// Round 4
// 1508.969 us; speedup vs baseline: 1.0380x; 1.0380x over previous
//
#include <hip/hip_runtime.h>
#include <hip/hip_bf16.h>

#define HWs 50176      // 224*224
#define WID 224
#define OHW 200704     // 448*448

// ---------------- K0: transpose conv weights OIHW[oc][ic][tap] -> [ic*9+tap][oc]
__global__ void k_wt(const float* __restrict__ w_head, const float* __restrict__ w_blk,
                     float* __restrict__ wt) {
  int l = blockIdx.y;
  int i = blockIdx.x * 256 + threadIdx.x;
  if (i >= 90000) return;
  const float* src = (l == 0) ? w_head : (w_blk + (l - 1) * 90000);
  int oc = i / 900, rem = i - oc * 900;       // rem = ic*9+tap
  wt[l * 90000 + rem * 100 + oc] = src[i];
}

// ---------------- K1: bilinear warp of feat_0/feat_1 + concat into x_in (100 planes fp32)
__global__ void k_warp(const float* __restrict__ f0, const float* __restrict__ f1,
                       const float* __restrict__ fd, const float* __restrict__ fl,
                       float* __restrict__ xin) {
  int p = blockIdx.x * 256 + threadIdx.x;          // 196*256 == 50176 exact
  int y = p / WID, x = p - y * WID;
  float fx0 = fl[p];
  float fy0 = fl[HWs + p];
  float fx1 = fl[2 * HWs + p];
  float fy1 = fl[3 * HWs + p];

  #pragma unroll
  for (int img = 0; img < 2; ++img) {
    const float* src = img ? f1 : f0;
    float fx = img ? fx1 : fx0;
    float fy = img ? fy1 : fy0;
    float px = (float)x + fx, py = (float)y + fy;
    float x0f = floorf(px), y0f = floorf(py);
    float wx = px - x0f, wy = py - y0f;
    int x0 = (int)fminf(fmaxf(x0f,       0.f), 223.f);
    int x1 = (int)fminf(fmaxf(x0f + 1.f, 0.f), 223.f);
    int y0 = (int)fminf(fmaxf(y0f,       0.f), 223.f);
    int y1 = (int)fminf(fmaxf(y0f + 1.f, 0.f), 223.f);
    float w00 = (1.f - wx) * (1.f - wy), w01 = wx * (1.f - wy);
    float w10 = (1.f - wx) * wy,         w11 = wx * wy;
    int i00 = y0 * WID + x0, i01 = y0 * WID + x1;
    int i10 = y1 * WID + x0, i11 = y1 * WID + x1;
    float* dst = xin + img * 32 * HWs;
    for (int c = 0; c < 32; ++c) {
      const float* pl = src + c * HWs;
      dst[c * HWs + p] = w00 * pl[i00] + w01 * pl[i01]
                       + w10 * pl[i10] + w11 * pl[i11];
    }
  }
  for (int c = 0; c < 32; ++c) xin[(64 + c) * HWs + p] = fd[c * HWs + p];
  xin[96 * HWs + p] = fx0; xin[97 * HWs + p] = fy0;
  xin[98 * HWs + p] = fx1; xin[99 * HWs + p] = fy1;
}

// ---------------- K2: 3x3 conv partial over 50 ics, all 100 oc, 8x8 px tile.
// grid (28,28,2): z picks ic half; 1568 blocks -> ~6 blocks/CU (vs 3 before).
// wave q computes oc [25q,25q+25); weights via wave-uniform s_load from wt.
__global__ __launch_bounds__(256, 8) void k_conv(
    const float* __restrict__ in, const float* __restrict__ wt,
    float* __restrict__ pA, float* __restrict__ pB) {
  __shared__ float patch[5000];                    // [50 ic][10*10], 20000 B
  int tid = threadIdx.x;
  int bx = blockIdx.x, by = blockIdx.y;
  int icbase = blockIdx.z * 50;
  float* pout = blockIdx.z ? pB : pA;
  int ox = bx * 8 - 1, oy = by * 8 - 1;

  for (int i = tid; i < 5000; i += 256) {
    int ic = i / 100, rem = i - ic * 100;
    int ry = rem / 10, rx = rem - ry * 10;
    int gy = oy + ry, gx = ox + rx;
    float v = 0.f;
    if ((unsigned)gy < 224u && (unsigned)gx < 224u)
      v = in[(icbase + ic) * HWs + gy * WID + gx];
    patch[i] = v;
  }
  __syncthreads();

  int lane = tid & 63;
  int ocq = __builtin_amdgcn_readfirstlane(tid >> 6);   // wave-uniform 0..3
  int px = lane & 7, py = lane >> 3;
  const float* wq = wt + icbase * 900 + 25 * ocq;  // + ic*900 + tap*100 + o

  float acc[25];
  #pragma unroll
  for (int o = 0; o < 25; ++o) acc[o] = 0.f;

  for (int ic = 0; ic < 50; ++ic) {
    const float* pp = patch + ic * 100 + py * 10 + px;
    const float* wic = wq + ic * 900;
    #pragma unroll
    for (int dy = 0; dy < 3; ++dy) {
      #pragma unroll
      for (int dx = 0; dx < 3; ++dx) {
        float pv = pp[dy * 10 + dx];
        const float* w25 = wic + (dy * 3 + dx) * 100;
        #pragma unroll
        for (int o = 0; o < 25; ++o)
          acc[o] = fmaf(w25[o], pv, acc[o]);
      }
    }
  }

  int gx0 = bx * 8 + px, gy0 = by * 8 + py;
  #pragma unroll
  for (int o = 0; o < 25; ++o)
    pout[(25 * ocq + o) * HWs + gy0 * WID + gx0] = acc[o];
}

// ---------------- K3: fused partial-combine + PReLU*mask + activation write
//                      + incremental einsum accumulate into xlast.
__global__ void k_post(const float* __restrict__ pA, const float* __restrict__ pB,
                       const float* __restrict__ avec, const float* __restrict__ mask,
                       const float* __restrict__ wlast, const float* __restrict__ blast,
                       float* __restrict__ xact, float* __restrict__ xlast,
                       int base, int init) {
  __shared__ __align__(16) float wl[100 * 36];     // [il][o], 14.4KB
  __shared__ float al[100];
  int tid = threadIdx.x;
  for (int j = tid; j < 100 * 36; j += 256) {
    int il = j / 36, o = j - il * 36;
    wl[j] = wlast[o * 500 + base + il];
  }
  if (tid < 100) al[tid] = avec[tid];
  __syncthreads();
  int p = blockIdx.x * 256 + tid;
  float m = mask[p];
  float acc[36];
  #pragma unroll
  for (int o = 0; o < 36; ++o) acc[o] = init ? blast[o] : xlast[o * HWs + p];
  for (int oc = 0; oc < 100; ++oc) {
    float z = pA[oc * HWs + p] + pB[oc * HWs + p];
    float v = (z >= 0.f ? z : al[oc] * z) * m;
    xact[oc * HWs + p] = v;
    const float4* wp = (const float4*)&wl[oc * 36];
    #pragma unroll
    for (int j = 0; j < 9; ++j) {
      float4 t = wp[j];
      acc[4*j]   += t.x * v;
      acc[4*j+1] += t.y * v;
      acc[4*j+2] += t.z * v;
      acc[4*j+3] += t.w * v;
    }
  }
  #pragma unroll
  for (int o = 0; o < 36; ++o) xlast[o * HWs + p] = acc[o];
}

// ---------------- K4: smn = conv3x3(xlast[4:36], w_mask) + b_mask (2 ch), fp64 accum
__global__ void k_smn(const float* __restrict__ xlast, const float* __restrict__ wmask,
                      const float* __restrict__ bmask, float* __restrict__ smn) {
  __shared__ float wm[576];
  int tid = threadIdx.x;
  for (int j = tid; j < 576; j += 256) wm[j] = wmask[j];
  __syncthreads();
  int p = blockIdx.x * 256 + tid;
  int y = p / WID, x = p - y * WID;
  double a0 = 0.0, a1 = 0.0;
  for (int ic = 0; ic < 32; ++ic) {
    const float* pl = xlast + (4 + ic) * HWs;
    #pragma unroll
    for (int dy = -1; dy <= 1; ++dy) {
      int gy = y + dy;
      if ((unsigned)gy < 224u) {
        #pragma unroll
        for (int dx = -1; dx <= 1; ++dx) {
          int gx = x + dx;
          if ((unsigned)gx < 224u) {
            double v = (double)pl[gy * WID + gx];
            int t = (dy + 1) * 3 + (dx + 1);
            a0 += (double)wm[ic * 9 + t] * v;        // oc 0
            a1 += (double)wm[288 + ic * 9 + t] * v;  // oc 1
          }
        }
      }
    }
  }
  smn[p]       = (float)(a0 + (double)bmask[0]);
  smn[HWs + p] = (float)(a1 + (double)bmask[1]);
}

// ---------------- K5: 2x bilinear upsample (jax.image.resize 'linear') + mask compare
__global__ void k_upsample(const float* __restrict__ xlast, const float* __restrict__ smn,
                           const float* __restrict__ smask, float* __restrict__ out) {
  int q = blockIdx.x * 256 + threadIdx.x;          // 784*256 == 200704 exact
  int oy = q / 448, ox = q - oy * 448;
  int ky = oy >> 1, kx = ox >> 1;
  int r0, r1, c0, c1; float wy0, wy1, wx0, wx1;
  if (oy & 1) { r0 = ky; r1 = (ky < 223) ? ky + 1 : 223; wy0 = 0.75f; wy1 = 0.25f; }
  else        { r0 = (ky > 0) ? ky - 1 : 0; r1 = ky;     wy0 = 0.25f; wy1 = 0.75f; }
  if (ox & 1) { c0 = kx; c1 = (kx < 223) ? kx + 1 : 223; wx0 = 0.75f; wx1 = 0.25f; }
  else        { c0 = (kx > 0) ? kx - 1 : 0; c1 = kx;     wx0 = 0.25f; wx1 = 0.75f; }
  float w00 = wy0 * wx0, w01 = wy0 * wx1, w10 = wy1 * wx0, w11 = wy1 * wx1;
  int i00 = r0 * WID + c0, i01 = r0 * WID + c1, i10 = r1 * WID + c0, i11 = r1 * WID + c1;
  for (int ch = 0; ch < 36; ++ch) {
    const float* pl = xlast + ch * HWs;
    out[ch * OHW + q] = w00 * pl[i00] + w01 * pl[i01] + w10 * pl[i10] + w11 * pl[i11];
  }
  double s0 = (double)w00 * smn[i00] + (double)w01 * smn[i01]
            + (double)w10 * smn[i10] + (double)w11 * smn[i11];
  const float* s1p = smn + HWs;
  double s1 = (double)w00 * s1p[i00] + (double)w01 * s1p[i01]
            + (double)w10 * s1p[i10] + (double)w11 * s1p[i11];
  float mu = smask[ky * WID + kx];
  out[36 * OHW + q] = (s0 > s1) ? mu : 0.f;
}

extern "C" void kernel_launch(void* const* d_in, const int* in_sizes, int n_in,
                              void* d_out, int out_size, void* d_ws, size_t ws_size,
                              hipStream_t stream) {
  const float* feat0   = (const float*)d_in[0];
  const float* feat1   = (const float*)d_in[1];
  const float* featd   = (const float*)d_in[2];
  const float* flow    = (const float*)d_in[3];
  const float* smask   = (const float*)d_in[4];
  const float* w_head  = (const float*)d_in[5];
  const float* a_head  = (const float*)d_in[6];
  const float* w_blk   = (const float*)d_in[7];
  const float* a_blk   = (const float*)d_in[8];
  const float* w_last  = (const float*)d_in[9];
  const float* b_last  = (const float*)d_in[10];
  const float* w_mask  = (const float*)d_in[11];
  const float* b_mask  = (const float*)d_in[12];

  // ws layout: act0/act1 ping-pong + partials pA/pB + xlast + smn + wt (~90 MB)
  float* act0  = (float*)d_ws;            // 100 planes
  float* act1  = act0 + 100 * HWs;        // 100 planes
  float* pA    = act1 + 100 * HWs;        // 100 planes
  float* pB    = pA   + 100 * HWs;        // 100 planes
  float* xlast = pB   + 100 * HWs;        // 36 planes
  float* smn   = xlast + 36 * HWs;        // 2 planes
  float* wt    = smn + 2 * HWs;           // 5*90000 floats

  k_wt<<<dim3(352, 5), 256, 0, stream>>>(w_head, w_blk, wt);
  k_warp<<<196, 256, 0, stream>>>(feat0, feat1, featd, flow, act0);

  dim3 cgrid(28, 28, 2);
  // head: act0 -> partials -> act1, einsum slice 0 (init)
  k_conv<<<cgrid, 256, 0, stream>>>(act0, wt, pA, pB);
  k_post<<<196, 256, 0, stream>>>(pA, pB, a_head, smask, w_last, b_last,
                                  act1, xlast, 0, 1);
  // blocks: ping-pong act1 <-> act0
  float* src = act1; float* dst = act0;
  for (int l = 0; l < 4; ++l) {
    k_conv<<<cgrid, 256, 0, stream>>>(src, wt + (l + 1) * 90000, pA, pB);
    k_post<<<196, 256, 0, stream>>>(pA, pB, a_blk + l * 100, smask, w_last, b_last,
                                    dst, xlast, (l + 1) * 100, 0);
    float* t = src; src = dst; dst = t;
  }

  k_smn<<<196, 256, 0, stream>>>(xlast, w_mask, b_mask, smn);
  k_upsample<<<784, 256, 0, stream>>>(xlast, smn, smask, (float*)d_out);
}